// Round 8
// baseline (1726.294 us; speedup 1.0000x reference)
//
#include <hip/hip_runtime.h>
#include <hip/hip_bf16.h>
#include <math.h>

// Problem dims (fixed by reference)
#define T_STEPS 512
#define BATCH   64
#define DIN     256
#define HID     1024
#define DOUT    256

typedef __attribute__((ext_vector_type(8))) _Float16 f16x8;
typedef __attribute__((ext_vector_type(4))) float    f32x4;
typedef __attribute__((ext_vector_type(4))) int      i32x4;
typedef unsigned long long ull;

static __device__ __forceinline__ unsigned short f2h_bits(float f) {
    union { _Float16 h; unsigned short u; } v; v.h = (_Float16)f; return v.u;
}
static __device__ __forceinline__ float h2f_bits(unsigned short u) {
    union { unsigned short u; _Float16 h; } v; v.u = u; return (float)v.h;
}

// fast tanh: 1 - 2/(exp(2|x|)+1), native v_exp/v_rcp (~1e-6 abs err, exact sat at +-1)
static __device__ __forceinline__ float fast_tanh(float x) {
    float ax = __builtin_fabsf(x);
    float e  = __expf(2.0f * ax);
    float r  = 1.0f - 2.0f * __builtin_amdgcn_rcpf(e + 1.0f);
    return __builtin_copysignf(r, x);
}

// Coherent (cross-XCD) ops: agent-scope relaxed atomics -> sc0|sc1 (L2-bypass /
// write-through to MALL). Protocol mechanics proven R1/R7 (passed).
static __device__ __forceinline__ void coh_store8(ull* p, ull v) {
    __hip_atomic_store(p, v, __ATOMIC_RELAXED, __HIP_MEMORY_SCOPE_AGENT);
}
static __device__ __forceinline__ unsigned coh_load4(const unsigned* p) {
    return __hip_atomic_load(p, __ATOMIC_RELAXED, __HIP_MEMORY_SCOPE_AGENT);
}
static __device__ __forceinline__ void coh_store4(unsigned* p, unsigned v) {
    __hip_atomic_store(p, v, __ATOMIC_RELAXED, __HIP_MEMORY_SCOPE_AGENT);
}

// ---------------- convert Wx -> WxT fp16 hi/lo planes ----------------
__global__ __launch_bounds__(256) void convert_wxt(const float* __restrict__ Wx,
                                                   unsigned short* __restrict__ wxt_hi,
                                                   unsigned short* __restrict__ wxt_lo) {
    int o = blockIdx.x * 256 + threadIdx.x;  // 262144 total
    int d = o & (DIN - 1);
    int j = o >> 8;
    float f = Wx[(size_t)d * HID + j];
    _Float16 hi = (_Float16)f;
    _Float16 lo = (_Float16)(f - (float)hi);
    union { _Float16 h; unsigned short u; } a, b;
    a.h = hi; b.h = lo;
    wxt_hi[(size_t)j * DIN + d] = a.u;
    wxt_lo[(size_t)j * DIN + d] = b.u;
}

// ---------------- pre = x @ Wx + b, in the rnn consumer's C-frag unit layout ---
// 8-B unit for (ts, row-group rr, col16 c16, lane lc): 4 fp16 =
//   pre[ts][16rr + 4*(lc>>4) + {0..3}][16*c16 + (lc&15)]
// (matches MFMA 16x16 C-frag: lane lc holds rows 4*(lc>>4)+reg, col lc&15)
// 2-term fp16 split: x_hi*W_hi + x_hi*W_lo.
__global__ __launch_bounds__(256) void gemm_pre(const float* __restrict__ x,
                                                const unsigned short* __restrict__ wxt_hi,
                                                const unsigned short* __restrict__ wxt_lo,
                                                const float* __restrict__ bias,
                                                ull* __restrict__ pre_r) {
    __shared__ unsigned short ldsP[64 * 68];   // 64 rows x 64 cols fp16, stride 68
    int t = blockIdx.x, y = blockIdx.y;        // timestep t, cols [64y..)
    int wave = threadIdx.x >> 6, lane = threadIdx.x & 63;
    int l15 = lane & 15, lkq = lane >> 4;
    int nb = y * 64;

    f32x4 acc[4] = {};
    const float* aptr = x + (size_t)(t * 64 + wave * 16 + l15) * DIN + lkq * 8;
#pragma unroll
    for (int ks = 0; ks < 8; ++ks) {
        float4 f0 = *(const float4*)(aptr + ks * 32);
        float4 f1 = *(const float4*)(aptr + ks * 32 + 4);
        union { _Float16 f[8]; f16x8 h; } uhi;
        uhi.f[0] = (_Float16)f0.x; uhi.f[1] = (_Float16)f0.y;
        uhi.f[2] = (_Float16)f0.z; uhi.f[3] = (_Float16)f0.w;
        uhi.f[4] = (_Float16)f1.x; uhi.f[5] = (_Float16)f1.y;
        uhi.f[6] = (_Float16)f1.z; uhi.f[7] = (_Float16)f1.w;
#pragma unroll
        for (int nt = 0; nt < 4; ++nt) {
            size_t boff = (size_t)(nb + nt * 16 + l15) * DIN + ks * 32 + lkq * 8;
            f16x8 bhi = *(const f16x8*)(wxt_hi + boff);
            f16x8 blo = *(const f16x8*)(wxt_lo + boff);
            acc[nt] = __builtin_amdgcn_mfma_f32_16x16x32_f16(uhi.h, bhi, acc[nt], 0, 0, 0);
            acc[nt] = __builtin_amdgcn_mfma_f32_16x16x32_f16(uhi.h, blo, acc[nt], 0, 0, 0);
        }
    }
#pragma unroll
    for (int nt = 0; nt < 4; ++nt) {
        float bb = bias[nb + nt * 16 + l15];
#pragma unroll
        for (int reg = 0; reg < 4; ++reg)
            ldsP[(16 * wave + lkq * 4 + reg) * 68 + nt * 16 + l15] = f2h_bits(acc[nt][reg] + bb);
    }
    __syncthreads();
    // epilogue: 1024 C-frag units (rr, cc, lc); 4 scattered u16 LDS reads each.
#pragma unroll
    for (int i = 0; i < 4; ++i) {
        int u = threadIdx.x + 256 * i;
        int rr = u >> 8, cc = (u >> 6) & 3, lc = u & 63;
        int hi2 = lc >> 4, l15c = lc & 15;
        int row0 = 16 * rr + 4 * hi2, colL = 16 * cc + l15c;
        union { unsigned short s[4]; ull u8; } vv;
        vv.s[0] = ldsP[(row0 + 0) * 68 + colL];
        vv.s[1] = ldsP[(row0 + 1) * 68 + colL];
        vv.s[2] = ldsP[(row0 + 2) * 68 + colL];
        vv.s[3] = ldsP[(row0 + 3) * 68 + colL];
        pre_r[((size_t)(t * 4 + rr) * 64 + (y * 4 + cc)) * 64 + lc] = vv.u8;
    }
}

// ---------------- persistent recurrence: 1 wave/block, full-K per wave ---------
// 256 blocks x 64 threads. wid = blockIdx.x: r = wid>>6 (rows [16r..16r+16)),
// c16 = wid&63 (cols [16*c16..+16)). Wave holds Wh[K=1024][16 cols] in regs
// (bfr, 128 VGPR) and computes its 16x16 output tile COMPLETELY: 32 MFMA over
// full K -> no cross-wave reduce, no barrier, fully self-paced.
// h buffer layout (per buffer, 128 KB): unit16(r, kc, m) at (r*2048+kc*16+m)*16
//   = h[16r+m][8kc..8kc+8)   (same as R7 -> out_gemm unchanged)
// Per step: poll 64 wave-flags of row-group r (1 load/lane + ballot) -> 32
// sc0sc1 dwordx4 loads staged in 128 VGPR, counted vmcnt(24/16/8/0) with MFMA
// interleave -> +pre (C-frag) -> tanh -> wave-local LDS transpose (C-frag ->
// row-major 8B) -> coherent 8B store -> fence (vmcnt drain) -> flag t+1.
// Overwrite safety (1-level): flag_V >= t means V's h_{t-1} LOADS drained
// (fence is vmcnt(0)); writer of h_{t+1} into buf[(t+1)%3] (holds h_{t-2})
// observed all flags >= t, so all reads of h_{t-2} completed.
__global__ __launch_bounds__(64, 1) void rnn_persistent(const float* __restrict__ Wh,
                                                        const ull* __restrict__ pre_r,
                                                        unsigned short* __restrict__ hbuf,
                                                        unsigned* __restrict__ flags) {
    __shared__ unsigned short tile[16 * 20];   // 640 B, padded stride 20
    const int wid = blockIdx.x;
    const int r = wid >> 6, c16 = wid & 63;
    const int lane = threadIdx.x;
    const int l15 = lane & 15, hi = lane >> 4;
    const int p = hi & 1, q = hi >> 1;

    // One-time: B-fragments Wh[k][16*c16 + l15], full K=1024 -> 128 VGPR.
    f16x8 bfr[32];
#pragma unroll
    for (int ksl = 0; ksl < 32; ++ksl) {
        union { _Float16 f[8]; f16x8 h; } u;
        int k0 = ksl * 32 + hi * 8;
        int col = c16 * 16 + l15;
#pragma unroll
        for (int j = 0; j < 8; ++j)
            u.f[j] = (_Float16)Wh[(size_t)(k0 + j) * HID + col];
        bfr[ksl] = u.h;
    }

    char* hb = (char*)hbuf;               // 3 buffers x 128 KB
    const char* hc = hb + 131072;         // read  at t=1 (h_1)
    char*       hn = hb + 2 * 131072;     // write at t=1 (h_2)
    char*       hx = hb;                  // write at t=2

    // store: unit16(m=l15, kc=2*c16+p) half q
    const size_t st_off = (size_t)(r * 2048 + (2 * c16 + p) * 16 + l15) * 16 + q * 8;
    // load (per ksl): unit16(m=l15, kc=ksl*4+hi)
    const size_t ld_off = (size_t)r * 32768 + (size_t)hi * 256 + (size_t)l15 * 16;

    const ull* preBase = pre_r + ((size_t)r * 64 + c16) * 64 + lane;
#define PRE_AT(ts) preBase[(size_t)(ts) * 16384]

    const unsigned* pollP = &flags[r * 64 + lane];

    // t = 0: h1 = tanh(pre0) (h0 == 0) -> buf1, flag 1.
    {
        union { _Float16 f[4]; ull u; } pv; pv.u = PRE_AT(0);
#pragma unroll
        for (int reg = 0; reg < 4; ++reg)
            tile[(4 * hi + reg) * 20 + l15] = f2h_bits(fast_tanh((float)pv.f[reg]));
        __syncthreads();
        ull v8 = *(const ull*)&tile[l15 * 20 + 8 * p + 4 * q];
        __syncthreads();
        coh_store8((ull*)(hb + 131072 + st_off), v8);
        __builtin_amdgcn_fence(__ATOMIC_RELEASE, "workgroup");   // vmcnt drain
        if (lane == 0) coh_store4(&flags[wid], 1u);
    }

    ull pv_next = PRE_AT(1);

    for (int t = 1; t <= 510; ++t) {
        union { _Float16 f[4]; ull u; } pvc; pvc.u = pv_next;

        // Poll all 64 wave-flags of row-group r.
        {
            const unsigned tt = (unsigned)t;
            for (;;) {
                unsigned v = coh_load4(pollP);
                if (__ballot(v >= tt) == ~0ull) break;
            }
        }

        // 32 x 16B L2-bypassing loads, all in flight; counted vmcnt + MFMA.
        i32x4 a[32];
        const char* abase = hc + ld_off;
#pragma unroll
        for (int ksl = 0; ksl < 32; ++ksl)
            asm volatile("global_load_dwordx4 %0, %1, off sc0 sc1"
                         : "=v"(a[ksl])
                         : "v"((const void*)(abase + (size_t)ksl * 1024)));

        f32x4 acc0 = {}, acc1 = {}, acc2 = {}, acc3 = {};
#pragma unroll
        for (int gph = 0; gph < 4; ++gph) {
            if (gph == 0) asm volatile("s_waitcnt vmcnt(24)" ::: "memory");
            else if (gph == 1) asm volatile("s_waitcnt vmcnt(16)" ::: "memory");
            else if (gph == 2) asm volatile("s_waitcnt vmcnt(8)" ::: "memory");
            else asm volatile("s_waitcnt vmcnt(0)" ::: "memory");
            __builtin_amdgcn_sched_barrier(0);
#pragma unroll
            for (int k2 = 0; k2 < 8; k2 += 4) {
                int ksl = gph * 8 + k2;
                union { i32x4 i; f16x8 h; } av0, av1, av2, av3;
                av0.i = a[ksl]; av1.i = a[ksl + 1]; av2.i = a[ksl + 2]; av3.i = a[ksl + 3];
                acc0 = __builtin_amdgcn_mfma_f32_16x16x32_f16(av0.h, bfr[ksl],     acc0, 0, 0, 0);
                acc1 = __builtin_amdgcn_mfma_f32_16x16x32_f16(av1.h, bfr[ksl + 1], acc1, 0, 0, 0);
                acc2 = __builtin_amdgcn_mfma_f32_16x16x32_f16(av2.h, bfr[ksl + 2], acc2, 0, 0, 0);
                acc3 = __builtin_amdgcn_mfma_f32_16x16x32_f16(av3.h, bfr[ksl + 3], acc3, 0, 0, 0);
            }
        }
        __builtin_amdgcn_sched_barrier(0);

        // Combine chains + pre + tanh (C-frag: rows 4*hi+reg, col l15).
        f32x4 s = (acc0 + acc1) + (acc2 + acc3);
#pragma unroll
        for (int reg = 0; reg < 4; ++reg)
            tile[(4 * hi + reg) * 20 + l15] = f2h_bits(fast_tanh(s[reg] + (float)pvc.f[reg]));
        __syncthreads();   // 1-wave block: lgkmcnt drain + trivial barrier
        ull v8 = *(const ull*)&tile[l15 * 20 + 8 * p + 4 * q];
        __syncthreads();
        coh_store8((ull*)(hn + st_off), v8);

        __builtin_amdgcn_fence(__ATOMIC_RELEASE, "workgroup");   // vmcnt drain
        if (t < 510 && lane == 0) coh_store4(&flags[wid], (unsigned)(t + 1));

        // Prefetch next pre AFTER the fence so the drain never waits on it.
        if (t < 510) pv_next = PRE_AT(t + 1);

        // rotate triple buffer
        const char* tmp = hc; hc = hn; hn = hx; hx = (char*)tmp;
    }
#undef PRE_AT
    // h_511 (== H[-2]) is in buf1; kernel end = implicit device release.
}

// ---------------- y = h_final @ W2 + b2 (h in unit16 layout, same as R7) -------
__global__ __launch_bounds__(256) void out_gemm(const unsigned short* __restrict__ hfin,
                                                const float* __restrict__ W2,
                                                const float* __restrict__ b2,
                                                float* __restrict__ out) {
    int b = blockIdx.x;        // batch row, 64
    int j = threadIdx.x;       // out col, 256
    int r = b >> 4, m = b & 15;
    float a[8] = {0.f, 0.f, 0.f, 0.f, 0.f, 0.f, 0.f, 0.f};
    for (int ks = 0; ks < 32; ++ks) {
#pragma unroll
        for (int lkq = 0; lkq < 4; ++lkq) {
            const unsigned short* ch =
                hfin + ((size_t)(r * 2048 + ks * 64 + lkq * 16 + m)) * 8;
            int k0 = ks * 32 + lkq * 8;
#pragma unroll
            for (int jj = 0; jj < 8; ++jj)
                a[jj] = fmaf(h2f_bits(ch[jj]), W2[(size_t)(k0 + jj) * DOUT + j], a[jj]);
        }
    }
    float acc = b2[j] + ((a[0] + a[1]) + (a[2] + a[3])) + ((a[4] + a[5]) + (a[6] + a[7]));
    out[(size_t)b * DOUT + j] = acc;
}

extern "C" void kernel_launch(void* const* d_in, const int* in_sizes, int n_in,
                              void* d_out, int out_size, void* d_ws, size_t ws_size,
                              hipStream_t stream) {
    const float* x  = (const float*)d_in[0];
    const float* Wx = (const float*)d_in[1];
    const float* Wh = (const float*)d_in[2];
    const float* b  = (const float*)d_in[3];
    const float* W2 = (const float*)d_in[4];
    const float* b2 = (const float*)d_in[5];
    float* out = (float*)d_out;

    // workspace carve (~69 MB)
    char* ws = (char*)d_ws;
    unsigned*       flags  = (unsigned*)ws;                                   // 1 KB (256 wave-flags)
    unsigned short* hbuf   = (unsigned short*)(ws + 4096);                    // 3 x 128 KB
    unsigned short* wxt_hi = (unsigned short*)(ws + 4096 + 393216);           // 0.5 MB
    unsigned short* wxt_lo = (unsigned short*)(ws + 4096 + 393216 + 524288);  // 0.5 MB
    ull*            pre_r  = (ull*)(ws + 4096 + 393216 + 2 * 524288);         // 64 MB

    (void)hipMemsetAsync(flags, 0, 4096, stream);
    convert_wxt<<<1024, 256, 0, stream>>>(Wx, wxt_hi, wxt_lo);
    gemm_pre<<<dim3(512, 16), 256, 0, stream>>>(x, wxt_hi, wxt_lo, b, pre_r);
    rnn_persistent<<<256, 64, 0, stream>>>(Wh, pre_r, hbuf, flags);
    out_gemm<<<64, 256, 0, stream>>>(hbuf + 65536, W2, b2, out);
}